// Round 3
// baseline (11.444 us; speedup 1.0000x reference)
//
#include <hip/hip_runtime.h>
#include <hip/hip_bf16.h>

#define VOCAB 32000
#define EMBED 128
#define NTOK  (4 * 2048)
#define TV    64            // vocab columns per block
#define PITCH 129           // LDS pitch (floats): 129 % 32 == 1 -> conflict-light

// out[t][:] = W[:, e[t]] + bias.
// Each block stages a coalesced, transposed, bias-fused [TV][EMBED] tile of W
// in LDS (W read exactly once, coalesced). After ONE barrier, each wave
// independently scans a 2048-id slice of e; __ballot finds ids in this block's
// vocab range; the wave cooperatively emits each matched token's 512B row
// (float2 per lane -> one coalesced 512B store). No atomics, no phase barriers.
__global__ __launch_bounds__(256) void embed_tile(const int* __restrict__ e,
                                                  const float* __restrict__ W,
                                                  const float* __restrict__ bias,
                                                  float* __restrict__ out) {
    __shared__ float ldsT[TV * PITCH];   // ldsT[c*PITCH + d] = W[d][v0+c] + bias[d]

    const int tid = threadIdx.x;
    const int v0  = blockIdx.x * TV;

    // Stage tile (transposed) with bias fused in.
    // Global reads: per wave-iteration 4 rows x 256B contiguous -> coalesced.
    // LDS store banks: (129*(c4+i) + d) % 32 == (c4+i+d) % 32 -> 2-way (free).
    {
        const int c4 = (tid & 15) << 2;   // column group 0,4,...,60
        const int dr = tid >> 4;          // row 0..15
        #pragma unroll
        for (int it = 0; it < 8; ++it) {
            const int d = dr + (it << 4);
            float4 w = *reinterpret_cast<const float4*>(&W[d * VOCAB + v0 + c4]);
            const float bd = bias[d];
            ldsT[(c4 + 0) * PITCH + d] = w.x + bd;
            ldsT[(c4 + 1) * PITCH + d] = w.y + bd;
            ldsT[(c4 + 2) * PITCH + d] = w.z + bd;
            ldsT[(c4 + 3) * PITCH + d] = w.w + bd;
        }
    }
    __syncthreads();

    const int lane  = tid & 63;
    const int wid   = tid >> 6;             // 4 waves per block
    const int wbase = wid * (NTOK / 4);     // 2048 ids per wave
    const int l2    = lane << 1;            // this lane's 2 dims

    #pragma unroll 4
    for (int s = 0; s < (NTOK / 4) / 64; ++s) {   // 32 steps of 64 ids
        const int t0  = wbase + (s << 6);
        const int tok = e[t0 + lane];             // coalesced 256B wave load
        const unsigned c = (unsigned)(tok - v0);
        unsigned long long m = __ballot(c < TV);
        while (m) {
            const int src = __builtin_ctzll(m);
            m &= m - 1;
            const int cc = __shfl((int)c, src, 64);
            const int tt = t0 + src;
            const float2 v = *reinterpret_cast<const float2*>(&ldsT[cc * PITCH + l2]);
            *reinterpret_cast<float2*>(&out[tt * EMBED + l2]) = v;  // 512B/wave store
        }
    }
}

extern "C" void kernel_launch(void* const* d_in, const int* in_sizes, int n_in,
                              void* d_out, int out_size, void* d_ws, size_t ws_size,
                              hipStream_t stream) {
    const int*   e    = (const int*)d_in[0];
    const float* W    = (const float*)d_in[1];
    const float* bias = (const float*)d_in[2];
    float*       out  = (float*)d_out;

    const int grid = VOCAB / TV;   // 500 blocks
    embed_tile<<<grid, 256, 0, stream>>>(e, W, bias, out);
}

// Round 4
// 9.955 us; speedup vs baseline: 1.1496x; 1.1496x over previous
//
#include <hip/hip_runtime.h>
#include <hip/hip_bf16.h>

#define VOCAB 32000
#define EMBED 128
#define NTOK  (4 * 2048)
#define TV    64            // vocab columns per block
#define PITCH 129           // LDS pitch (floats): bank = (c + d) % 32 -> 2-way max on stage

// out[t][:] = W[:, e[t]] + bias.
// Per block: (1) prefetch this wave's 2048 token ids into 8 int4 REGISTERS
// (issued before staging so e-loads and W-loads are in flight together),
// (2) stage a coalesced, transposed, bias-fused [TV][EMBED] W tile in LDS
// (W read exactly once, coalesced), (3) one barrier, (4) pure-register
// ballot scan finds the ~16 tokens in this block's vocab range; the wave
// cooperatively emits each matched token's 512B row (float2/lane, one
// coalesced store). No loads after the barrier except the emits.
__global__ __launch_bounds__(256) void embed_tile(const int* __restrict__ e,
                                                  const float* __restrict__ W,
                                                  const float* __restrict__ bias,
                                                  float* __restrict__ out) {
    __shared__ float ldsT[TV * PITCH];   // ldsT[c*PITCH + d] = W[d][v0+c] + bias[d]

    const int tid   = threadIdx.x;
    const int v0    = blockIdx.x * TV;
    const int lane  = tid & 63;
    const int wid   = tid >> 6;              // 4 waves
    const int wbase = wid * (NTOK / 4);      // 2048 ids per wave

    // (1) Prefetch e-slice into registers: 8 steps x 256 ids (int4/lane).
    int4 ebuf[8];
    #pragma unroll
    for (int s = 0; s < 8; ++s)
        ebuf[s] = *reinterpret_cast<const int4*>(&e[wbase + (s << 8) + (lane << 2)]);

    // (2) Stage W tile transposed into LDS with bias fused.
    {
        const int c4 = (tid & 15) << 2;   // column group 0,4,...,60
        const int dr = tid >> 4;          // row 0..15
        #pragma unroll
        for (int it = 0; it < 8; ++it) {
            const int d = dr + (it << 4);
            float4 w = *reinterpret_cast<const float4*>(&W[d * VOCAB + v0 + c4]);
            const float bd = bias[d];
            ldsT[(c4 + 0) * PITCH + d] = w.x + bd;
            ldsT[(c4 + 1) * PITCH + d] = w.y + bd;
            ldsT[(c4 + 2) * PITCH + d] = w.z + bd;
            ldsT[(c4 + 3) * PITCH + d] = w.w + bd;
        }
    }
    __syncthreads();

    // (3) Register-resident ballot scan + cooperative emit.
    const int l2 = lane << 1;            // this lane's 2 dims
    #pragma unroll
    for (int s = 0; s < 8; ++s) {
        const int tok[4] = {ebuf[s].x, ebuf[s].y, ebuf[s].z, ebuf[s].w};
        #pragma unroll
        for (int j = 0; j < 4; ++j) {
            const unsigned c = (unsigned)(tok[j] - v0);
            unsigned long long m = __ballot(c < TV);
            while (m) {
                const int src = __builtin_ctzll(m);
                m &= m - 1;
                const int cc = __shfl((int)c, src, 64);
                const int tt = wbase + (s << 8) + (src << 2) + j;
                const float2 v = *reinterpret_cast<const float2*>(&ldsT[cc * PITCH + l2]);
                *reinterpret_cast<float2*>(&out[tt * EMBED + l2]) = v;  // 512B/wave
            }
        }
    }
}

extern "C" void kernel_launch(void* const* d_in, const int* in_sizes, int n_in,
                              void* d_out, int out_size, void* d_ws, size_t ws_size,
                              hipStream_t stream) {
    const int*   e    = (const int*)d_in[0];
    const float* W    = (const float*)d_in[1];
    const float* bias = (const float*)d_in[2];
    float*       out  = (float*)d_out;

    const int grid = VOCAB / TV;   // 500 blocks
    embed_tile<<<grid, 256, 0, stream>>>(e, W, bias, out);
}